// Round 7
// baseline (23185.286 us; speedup 1.0000x reference)
//
#include <hip/hip_runtime.h>
#include <math.h>

typedef unsigned short u16;
typedef __attribute__((ext_vector_type(8))) short s8v;   // 8 x bf16 (4 VGPRs)
typedef __attribute__((ext_vector_type(4))) float f4v;   // MFMA accumulator
typedef __attribute__((ext_vector_type(4))) int   i4v;   // asm load payload

constexpr int kB    = 256;
constexpr int kT    = 512;
constexpr int kDIN  = 64;
constexpr int kH    = 512;
constexpr int kG3   = 1536;
constexpr int kNOUT = 128;
constexpr int kPlane = 8 * 2 * 16 * 512;   // u16 per A-frag plane (131072)

__device__ __forceinline__ u16 f2bf(float f) {   // round-to-nearest-even
  union { float f; unsigned u; } v; v.f = f;
  unsigned r = (v.u + 0x7FFFu + ((v.u >> 16) & 1u)) >> 16;
  return (u16)r;
}
__device__ __forceinline__ float fsig(float x) {
  x = fminf(fmaxf(x, -30.f), 30.f);
  float e = __expf(-x);
  return __fdividef(1.f, 1.f + e);
}
__device__ __forceinline__ float ftanh(float x) {
  x = fminf(fmaxf(x, -15.f), 15.f);
  float e = __expf(-2.f * x);
  return __fdividef(1.f - e, 1.f + e);
}

// Group barrier (16 blocks sharing one counter cacheline).
// RELAXED spin (no per-poll invalidate), one ACQUIRE load at the end.
__device__ __forceinline__ void gbar16(unsigned* bar, unsigned target) {
  __threadfence();      // release: drain stores, L2 writeback (agent scope)
  __syncthreads();      // whole block arrived with stores fenced
  if (threadIdx.x == 0) {
    __hip_atomic_fetch_add(bar, 1u, __ATOMIC_RELEASE, __HIP_MEMORY_SCOPE_AGENT);
    int guard = 0;
    while (__hip_atomic_load(bar, __ATOMIC_RELAXED, __HIP_MEMORY_SCOPE_AGENT) < target
           && ++guard < (1 << 21)) { }
    (void)__hip_atomic_load(bar, __ATOMIC_ACQUIRE, __HIP_MEMORY_SCOPE_AGENT);
  }
  __syncthreads();
}

// 16 A-fragment loads (16 B/lane each, kt stride 1024 B), L1/L2 bypass,
// one vmcnt(0) at the end — full memory-level parallelism.
__device__ __forceinline__ void load_afrag16(const u16* base, i4v a[16]) {
  asm volatile(
      "global_load_dwordx4 %0, %16, off sc0 sc1\n\t"
      "global_load_dwordx4 %1, %16, off offset:1024 sc0 sc1\n\t"
      "global_load_dwordx4 %2, %16, off offset:2048 sc0 sc1\n\t"
      "global_load_dwordx4 %3, %16, off offset:3072 sc0 sc1\n\t"
      "global_load_dwordx4 %4, %17, off sc0 sc1\n\t"
      "global_load_dwordx4 %5, %17, off offset:1024 sc0 sc1\n\t"
      "global_load_dwordx4 %6, %17, off offset:2048 sc0 sc1\n\t"
      "global_load_dwordx4 %7, %17, off offset:3072 sc0 sc1\n\t"
      "global_load_dwordx4 %8, %18, off sc0 sc1\n\t"
      "global_load_dwordx4 %9, %18, off offset:1024 sc0 sc1\n\t"
      "global_load_dwordx4 %10, %18, off offset:2048 sc0 sc1\n\t"
      "global_load_dwordx4 %11, %18, off offset:3072 sc0 sc1\n\t"
      "global_load_dwordx4 %12, %19, off sc0 sc1\n\t"
      "global_load_dwordx4 %13, %19, off offset:1024 sc0 sc1\n\t"
      "global_load_dwordx4 %14, %19, off offset:2048 sc0 sc1\n\t"
      "global_load_dwordx4 %15, %19, off offset:3072 sc0 sc1\n\t"
      "s_waitcnt vmcnt(0)"
      : "=&v"(a[0]), "=&v"(a[1]), "=&v"(a[2]), "=&v"(a[3]),
        "=&v"(a[4]), "=&v"(a[5]), "=&v"(a[6]), "=&v"(a[7]),
        "=&v"(a[8]), "=&v"(a[9]), "=&v"(a[10]), "=&v"(a[11]),
        "=&v"(a[12]), "=&v"(a[13]), "=&v"(a[14]), "=&v"(a[15])
      : "v"(base), "v"(base + 4 * 512), "v"(base + 8 * 512), "v"(base + 12 * 512)
      : "memory");
}

// ---------------------------------------------------------------------------
// Pre-swizzle w_hh [1536][512] fp32 -> per-block-slice B-fragment slabs (bf16).
// Slab layout: [jt 16][f 96][lane 64][8],  f = nt*16 + kt,  nt = g*2 + u.
// elem: row = g*512 + jt*32 + u*16 + (lane&15), k = kt*32 + (lane>>4)*8 + i
// ---------------------------------------------------------------------------
__global__ void build_wslab(const float* __restrict__ w, u16* __restrict__ d) {
  int idx  = blockIdx.x * 256 + threadIdx.x;   // 0..98303
  int lane = idx & 63, fg = idx >> 6;          // fg = jt*96 + f
  int jt = fg / 96, f = fg % 96;
  int nt = f >> 4, kt = f & 15;
  int g = nt >> 1, u = nt & 1;
  int row = g * 512 + jt * 32 + u * 16 + (lane & 15);
  int k0  = kt * 32 + (lane >> 4) * 8;
  const float* src = w + (size_t)row * 512 + k0;
  u16* dst = d + ((size_t)fg) * 512 + lane * 8;
#pragma unroll
  for (int i = 0; i < 8; i++) dst[i] = f2bf(src[i]);
}

// ---------------------------------------------------------------------------
// Persistent weight-resident recurrence. Regular launch, grid = 256 blocks
// (== CU count; co-resident by capacity), 256 threads (4 waves).
// Blocks 0..127: layer0 chunk c; 128..255: layer1 chunk c-1.
// Block (bt 0..7, jt 0..15): 32 batches x 32 j. Wave (mt=w>>1, u=w&1):
// 16 batches x 16 j, all 3 gates. Weights: 48 B-fragments/wave in VGPRs.
// h exchanged in MFMA A-FRAGMENT LAYOUT: hbuf plane [bt][mt][kt][lane][8]
// bf16; block (bt,jt) writes k-tile jt, reads all 16 kt for its bt.
// Reads are sc0|sc1 (L1/L2 bypass); writes plain + threadfence (R6-proven).
// hp (fp32 state) lives in 4 VGPRs/lane; no LDS at all.
// ---------------------------------------------------------------------------
__global__ __launch_bounds__(256, 1)
void coop_rec(int c, int TC, int nc, unsigned bar_base16, unsigned* bar,
              const float* __restrict__ xg0, const float* __restrict__ xg1,
              const u16* __restrict__ wslab0, const u16* __restrict__ wslab1,
              const float* __restrict__ bhh0, const float* __restrict__ bhh1,
              u16* __restrict__ h1seq, u16* __restrict__ hbuf,
              float* __restrict__ carry) {
  const int bid   = blockIdx.x;
  const int layer = bid >> 7;
  const int lb    = bid & 127;
  const int jt    = lb & 15, bt = lb >> 4;
  const int cc    = (layer == 0) ? c : c - 1;
  const bool active = (cc >= 0 && cc < nc);

  unsigned* mybar = bar + (size_t)(layer * 8 + bt) * 64;   // own cacheline

  if (!active) {               // keep the group's counter in lockstep
    for (int t = 0; t < TC; ++t)
      gbar16(mybar, bar_base16 + 16u * (unsigned)(t + 1));
    return;
  }

  const float* xg    = layer ? xg1 : xg0;
  const u16*  wslab  = layer ? wslab1 : wslab0;
  const float* bhh   = layer ? bhh1 : bhh0;
  float* mycarry = carry + (size_t)layer * kB * kH;

  const int tid  = threadIdx.x;
  const int wv   = tid >> 6, lane = tid & 63;
  const int mt   = wv >> 1, u = wv & 1;
  const int b0   = bt * 32;
  const int jl   = lane & 15;
  const int jg   = jt * 32 + u * 16 + jl;        // this lane's output j
  const int mrow = (lane >> 4) * 4;              // first of 4 batch rows

  // --- load this wave's 48 B-fragments into registers (once) ---
  s8v bfr[3][16];
  {
    const u16* base = wslab + (size_t)jt * 96 * 512;
#pragma unroll
    for (int g = 0; g < 3; ++g)
#pragma unroll
      for (int kt = 0; kt < 16; ++kt)
        bfr[g][kt] = *(const s8v*)&base[(size_t)((g * 2 + u) * 16 + kt) * 512 + lane * 8];
  }
  const float bh_r = bhh[jg], bh_z = bhh[512 + jg], bh_n = bhh[1024 + jg];

  // --- fp32 state for this lane's 4 (batch, j) outputs, from carry ---
  float hp[4];
#pragma unroll
  for (int r = 0; r < 4; ++r)
    hp[r] = mycarry[(size_t)(b0 + mt * 16 + mrow + r) * 512 + jg];

  // consumer fragment base (this wave's m-tile, kt=0), producer frag index
  const size_t cons_off = ((size_t)((bt * 2 + mt) * 16)) * 512 + lane * 8;
  const size_t prod_off = ((size_t)((bt * 2 + mt) * 16 + jt)) * 512 +
                          (size_t)(16 * (u * 2 + (jl >> 3))) * 8 + (jl & 7);

  for (int t = 0; t < TC; ++t) {
    // --- xg loads first (independent; drained by the asm's vmcnt(0)) ---
    float xv0[4], xv1[4], xv2[4];
#pragma unroll
    for (int r = 0; r < 4; ++r) {
      int b = b0 + mt * 16 + mrow + r;
      const float* xp = xg + ((size_t)b * TC + t) * kG3;
      xv0[r] = xp[jg]; xv1[r] = xp[512 + jg]; xv2[r] = xp[1024 + jg];
    }

    // --- A-fragments of h_{t-1}: 16 x dwordx4, L1/L2 bypass, one waitcnt ---
    const u16* plane = hbuf + (size_t)(layer * 2 + (t & 1)) * kPlane;
    i4v a[16];
    load_afrag16(plane + cons_off, a);

    // --- MFMA: 3 gates x 16 k-tiles (3 independent chains) ---
    f4v acc0 = {0.f, 0.f, 0.f, 0.f}, acc1 = acc0, acc2 = acc0;
#pragma unroll
    for (int kt = 0; kt < 16; ++kt) {
      const s8v av = __builtin_bit_cast(s8v, a[kt]);
      acc0 = __builtin_amdgcn_mfma_f32_16x16x32_bf16(av, bfr[0][kt], acc0, 0, 0, 0);
      acc1 = __builtin_amdgcn_mfma_f32_16x16x32_bf16(av, bfr[1][kt], acc1, 0, 0, 0);
      acc2 = __builtin_amdgcn_mfma_f32_16x16x32_bf16(av, bfr[2][kt], acc2, 0, 0, 0);
    }

    // --- gates + state update; store h_t into next parity plane (A-layout) ---
    u16* planeN = hbuf + (size_t)(layer * 2 + ((t + 1) & 1)) * kPlane;
#pragma unroll
    for (int r = 0; r < 4; ++r) {
      float rr = fsig(xv0[r] + acc0[r] + bh_r);
      float zz = fsig(xv1[r] + acc1[r] + bh_z);
      float nn = ftanh(xv2[r] + rr * (acc2[r] + bh_n));
      float hn = (1.f - zz) * nn + zz * hp[r];
      hp[r] = hn;
      u16 hb = f2bf(hn);
      planeN[prod_off + (size_t)(mrow + r) * 8] = hb;
      if (layer == 0)
        h1seq[((size_t)(b0 + mt * 16 + mrow + r) * TC + t) * 512 + jg] = hb;
    }
    gbar16(mybar, bar_base16 + 16u * (unsigned)(t + 1));
  }

  // --- carry writeback (fp32) ---
#pragma unroll
  for (int r = 0; r < 4; ++r)
    mycarry[(size_t)(b0 + mt * 16 + mrow + r) * 512 + jg] = hp[r];
}

// ---- GEMM: C[r][1536] = A[r][K] @ W[1536][K]^T + bias (bf16 MFMA) ----
// Row r -> (b = r/TC, t = r%TC); rowptr = A + (b*Abstride + Atoff + t)*K
__device__ void gemm_role(int idx, int TC,
                          const float* __restrict__ Af, const u16* __restrict__ Ab,
                          int Abstride, int Atoff, int K,
                          const float* __restrict__ Bf, const float* __restrict__ bias,
                          float* __restrict__ C, char* smem) {
  u16* As = (u16*)smem;            // [128][40]
  u16* Bs = As + 128 * 40;         // [128][40]
  const int tid = threadIdx.x;
  const int mt = idx / 12, nt = idx % 12;
  const int m0 = mt * 128, n0 = nt * 128;
  const int w = tid >> 6, lane = tid & 63;
  const int wm = w & 1, wn = w >> 1;
  const int ra = tid >> 2, koff = (tid & 3) * 8;

  const int r = m0 + ra;
  const size_t aoff = ((size_t)(r / TC) * Abstride + Atoff + (r % TC)) * K;
  const float* arowF = Af ? Af + aoff : nullptr;
  const u16*  arowB = Ab ? Ab + aoff : nullptr;
  const float* browF = Bf + (size_t)(n0 + ra) * K;

  f4v acc[4][2];
#pragma unroll
  for (int i = 0; i < 4; i++)
#pragma unroll
    for (int jn = 0; jn < 2; jn++) acc[i][jn] = (f4v){0.f, 0.f, 0.f, 0.f};

  for (int k0 = 0; k0 < K; k0 += 32) {
    s8v av, bv;
    if (arowB) {
      av = *(const s8v*)(arowB + k0 + koff);
    } else {
      u16 tmp[8];
      const float* ap = arowF + k0 + koff;
#pragma unroll
      for (int i = 0; i < 8; i++) tmp[i] = f2bf(ap[i]);
      av = *(s8v*)tmp;
    }
    {
      u16 tmp[8];
      const float* bp = browF + k0 + koff;
#pragma unroll
      for (int i = 0; i < 8; i++) tmp[i] = f2bf(bp[i]);
      bv = *(s8v*)tmp;
    }
    __syncthreads();
    *(s8v*)&As[ra * 40 + koff] = av;
    *(s8v*)&Bs[ra * 40 + koff] = bv;
    __syncthreads();
    s8v af[4];
#pragma unroll
    for (int i = 0; i < 4; i++)
      af[i] = *(const s8v*)&As[(wm * 64 + i * 16 + (lane & 15)) * 40 + (lane >> 4) * 8];
#pragma unroll
    for (int jn = 0; jn < 2; jn++) {
      s8v bf = *(const s8v*)&Bs[(wn * 32 + jn * 16 + (lane & 15)) * 40 + (lane >> 4) * 8];
#pragma unroll
      for (int i = 0; i < 4; i++)
        acc[i][jn] = __builtin_amdgcn_mfma_f32_16x16x32_bf16(af[i], bf, acc[i][jn], 0, 0, 0);
    }
  }

#pragma unroll
  for (int jn = 0; jn < 2; jn++) {
    int n = n0 + wn * 32 + jn * 16 + (lane & 15);
    float bv2 = bias[n];
#pragma unroll
    for (int i = 0; i < 4; i++) {
      int mrow = m0 + wm * 64 + i * 16 + (lane >> 4) * 4;
#pragma unroll
      for (int reg = 0; reg < 4; reg++)
        C[(size_t)(mrow + reg) * kG3 + n] = acc[i][jn][reg] + bv2;
    }
  }
}

__global__ __launch_bounds__(512)
void gemm_kernel(int TC, const float* Af, const u16* Ab, int Abstride, int Atoff,
                 int K, const float* Bf, const float* bias, float* C) {
  __shared__ __align__(16) char smem[2 * 128 * 40 * 2];
  gemm_role(blockIdx.x, TC, Af, Ab, Abstride, Atoff, K, Bf, bias, C, smem);
}

// ---------------------------------------------------------------------------
__global__ __launch_bounds__(128)
void fc_kernel(const float* __restrict__ h, const float* __restrict__ wfc,
               const float* __restrict__ bfc, float* __restrict__ out) {
  const int b = blockIdx.x;
  const int n = threadIdx.x;
  const float* hrow = h + (size_t)b * kH;
  const float* wrow = wfc + (size_t)n * kH;
  float acc = 0.f;
#pragma unroll 4
  for (int k = 0; k < kH; k += 4) {
    const float4 hv = *(const float4*)&hrow[k];
    const float4 wv = *(const float4*)&wrow[k];
    acc = fmaf(hv.x, wv.x, acc); acc = fmaf(hv.y, wv.y, acc);
    acc = fmaf(hv.z, wv.z, acc); acc = fmaf(hv.w, wv.w, acc);
  }
  out[(size_t)b * kNOUT + n] = acc + bfc[n];
}

// ---------------------------------------------------------------------------
extern "C" void kernel_launch(void* const* d_in, const int* in_sizes, int n_in,
                              void* d_out, int out_size, void* d_ws, size_t ws_size,
                              hipStream_t stream) {
  const float* x     = (const float*)d_in[0];
  const float* w_ih0 = (const float*)d_in[1];
  const float* w_hh0 = (const float*)d_in[2];
  const float* b_ih0 = (const float*)d_in[3];
  const float* b_hh0 = (const float*)d_in[4];
  const float* w_ih1 = (const float*)d_in[5];
  const float* w_hh1 = (const float*)d_in[6];
  const float* b_ih1 = (const float*)d_in[7];
  const float* b_hh1 = (const float*)d_in[8];
  const float* w_fc  = (const float*)d_in[9];
  const float* b_fc  = (const float*)d_in[10];
  float* out = (float*)d_out;

  // workspace sizing (TC adaptive; TC=64 needs ~240 MB)
  auto need = [](int tc) -> size_t {
    size_t s = 0;
    s += 2 * (size_t)kB * tc * kG3 * 4;   // xg0 + xg1 fp32
    s += (size_t)kB * tc * kH * 2;        // h1seq bf16
    s += 2 * (size_t)kG3 * kH * 2;        // wslab x2
    s += 4 * (size_t)kPlane * 2;          // hbuf A-frag planes [2 layers][2 parity]
    s += 2 * (size_t)kB * kH * 4;         // carry fp32 x2
    s += 32768;
    return s;
  };
  int TC = 64;
  while (TC > 2 && need(TC) > ws_size) TC >>= 1;
  const int nc = kT / TC;

  char* p = (char*)d_ws;
  auto carve = [&](size_t bytes) {
    char* r = p; p += (bytes + 255) & ~(size_t)255; return r;
  };
  float* xg0   = (float*)carve((size_t)kB * TC * kG3 * 4);
  float* xg1   = (float*)carve((size_t)kB * TC * kG3 * 4);
  u16* h1seq   = (u16*)carve((size_t)kB * TC * kH * 2);
  u16* wslab0  = (u16*)carve((size_t)kG3 * kH * 2);
  u16* wslab1  = (u16*)carve((size_t)kG3 * kH * 2);
  u16* hbuf    = (u16*)carve(4 * (size_t)kPlane * 2);
  float* carry = (float*)carve(2 * (size_t)kB * kH * 4);
  unsigned* bar = (unsigned*)carve(32 * 64 * sizeof(unsigned));  // 32 cachelines

  // prologue: weight swizzle + zero h planes/carries + barrier counters
  build_wslab<<<384, 256, 0, stream>>>(w_hh0, wslab0);
  build_wslab<<<384, 256, 0, stream>>>(w_hh1, wslab1);
  hipMemsetAsync(hbuf, 0, 4 * (size_t)kPlane * 2 + 2 * (size_t)kB * kH * 4, stream);
  hipMemsetAsync(bar, 0, 32 * 64 * sizeof(unsigned), stream);

  const dim3 ggrid(2 * TC * 12);   // (256*TC/128) m-tiles x 12 n-tiles

  for (int c = 0; c <= nc; ++c) {
    if (c < nc) {
      // proj0(c): xg0 = x(chunk c) @ w_ih0^T + b_ih0
      gemm_kernel<<<ggrid, 512, 0, stream>>>(TC, x, nullptr, kT, c * TC, kDIN,
                                             w_ih0, b_ih0, xg0);
    }
    // persistent recurrence: rec0(c) blocks 0..127, rec1(c-1) blocks 128..255
    {
      unsigned base16 = (unsigned)c * 16u * (unsigned)TC;
      coop_rec<<<dim3(256), dim3(256), 0, stream>>>(
          c, TC, nc, base16, bar, xg0, xg1, wslab0, wslab1,
          b_hh0, b_hh1, h1seq, hbuf, carry);
    }
    if (c < nc) {
      // proj1(c): xg1 = h1seq(c) @ w_ih1^T + b_ih1
      gemm_kernel<<<ggrid, 512, 0, stream>>>(TC, nullptr, h1seq, TC, 0, kH,
                                             w_ih1, b_ih1, xg1);
    }
  }

  // final FC on layer-1 carry (fp32)
  fc_kernel<<<dim3(kB), dim3(kNOUT), 0, stream>>>(
      carry + (size_t)kB * kH, w_fc, b_fc, out);
}

// Round 8
// 3238.837 us; speedup vs baseline: 7.1585x; 7.1585x over previous
//
#include <hip/hip_runtime.h>
#include <math.h>

typedef unsigned short u16;
typedef __attribute__((ext_vector_type(8))) short s8v;   // 8 x bf16 (4 VGPRs)
typedef __attribute__((ext_vector_type(4))) float f4v;   // MFMA accumulator
typedef __attribute__((ext_vector_type(4))) int   i4v;   // asm load payload

constexpr int kB    = 256;
constexpr int kT    = 512;
constexpr int kDIN  = 64;
constexpr int kH    = 512;
constexpr int kG3   = 1536;
constexpr int kNOUT = 128;
constexpr int kPlane = 8 * 2 * 16 * 512;   // u16 per A-frag plane (131072)

__device__ __forceinline__ u16 f2bf(float f) {   // round-to-nearest-even
  union { float f; unsigned u; } v; v.f = f;
  unsigned r = (v.u + 0x7FFFu + ((v.u >> 16) & 1u)) >> 16;
  return (u16)r;
}
__device__ __forceinline__ float fsig(float x) {
  x = fminf(fmaxf(x, -30.f), 30.f);
  float e = __expf(-x);
  return __fdividef(1.f, 1.f + e);
}
__device__ __forceinline__ float ftanh(float x) {
  x = fminf(fmaxf(x, -15.f), 15.f);
  float e = __expf(-2.f * x);
  return __fdividef(1.f - e, 1.f + e);
}

// Fence-free group barrier (16 blocks / cacheline counter).
// Exchange data is sc0|sc1 (coherent at LLC) => NO buffer_wbl2 / buffer_inv
// needed; release = vmcnt(0) drain only, counter = relaxed agent atomics.
__device__ __forceinline__ void gbar16(unsigned* bar, unsigned target) {
  asm volatile("s_waitcnt vmcnt(0) lgkmcnt(0)" ::: "memory");
  __syncthreads();      // whole block arrived with stores drained
  if (threadIdx.x == 0) {
    __hip_atomic_fetch_add(bar, 1u, __ATOMIC_RELAXED, __HIP_MEMORY_SCOPE_AGENT);
    int guard = 0;
    while (__hip_atomic_load(bar, __ATOMIC_RELAXED, __HIP_MEMORY_SCOPE_AGENT) < target
           && ++guard < (1 << 20)) {
      __builtin_amdgcn_s_sleep(2);
    }
  }
  __syncthreads();
}

// 16 A-fragment loads (16 B/lane each, kt stride 1024 B), L1/L2 bypass,
// one vmcnt(0) at the end — full memory-level parallelism.
__device__ __forceinline__ void load_afrag16(const u16* base, i4v a[16]) {
  asm volatile(
      "global_load_dwordx4 %0, %16, off sc0 sc1\n\t"
      "global_load_dwordx4 %1, %16, off offset:1024 sc0 sc1\n\t"
      "global_load_dwordx4 %2, %16, off offset:2048 sc0 sc1\n\t"
      "global_load_dwordx4 %3, %16, off offset:3072 sc0 sc1\n\t"
      "global_load_dwordx4 %4, %17, off sc0 sc1\n\t"
      "global_load_dwordx4 %5, %17, off offset:1024 sc0 sc1\n\t"
      "global_load_dwordx4 %6, %17, off offset:2048 sc0 sc1\n\t"
      "global_load_dwordx4 %7, %17, off offset:3072 sc0 sc1\n\t"
      "global_load_dwordx4 %8, %18, off sc0 sc1\n\t"
      "global_load_dwordx4 %9, %18, off offset:1024 sc0 sc1\n\t"
      "global_load_dwordx4 %10, %18, off offset:2048 sc0 sc1\n\t"
      "global_load_dwordx4 %11, %18, off offset:3072 sc0 sc1\n\t"
      "global_load_dwordx4 %12, %19, off sc0 sc1\n\t"
      "global_load_dwordx4 %13, %19, off offset:1024 sc0 sc1\n\t"
      "global_load_dwordx4 %14, %19, off offset:2048 sc0 sc1\n\t"
      "global_load_dwordx4 %15, %19, off offset:3072 sc0 sc1\n\t"
      "s_waitcnt vmcnt(0)"
      : "=&v"(a[0]), "=&v"(a[1]), "=&v"(a[2]), "=&v"(a[3]),
        "=&v"(a[4]), "=&v"(a[5]), "=&v"(a[6]), "=&v"(a[7]),
        "=&v"(a[8]), "=&v"(a[9]), "=&v"(a[10]), "=&v"(a[11]),
        "=&v"(a[12]), "=&v"(a[13]), "=&v"(a[14]), "=&v"(a[15])
      : "v"(base), "v"(base + 4 * 512), "v"(base + 8 * 512), "v"(base + 12 * 512)
      : "memory");
}

// Coherent (LLC-direct) 2-byte store: keeps exchange data OUT of L2, so the
// step loop needs no cache-maintenance ops at all.
__device__ __forceinline__ void store_h_coherent(u16* addr, u16 val) {
  unsigned v = val;
  asm volatile("global_store_short %0, %1, off sc0 sc1"
               :: "v"(addr), "v"(v) : "memory");
}

// ---------------------------------------------------------------------------
// Pre-swizzle w_hh [1536][512] fp32 -> per-block-slice B-fragment slabs (bf16).
// Slab layout: [jt 16][f 96][lane 64][8],  f = nt*16 + kt,  nt = g*2 + u.
// elem: row = g*512 + jt*32 + u*16 + (lane&15), k = kt*32 + (lane>>4)*8 + i
// ---------------------------------------------------------------------------
__global__ void build_wslab(const float* __restrict__ w, u16* __restrict__ d) {
  int idx  = blockIdx.x * 256 + threadIdx.x;   // 0..98303
  int lane = idx & 63, fg = idx >> 6;          // fg = jt*96 + f
  int jt = fg / 96, f = fg % 96;
  int nt = f >> 4, kt = f & 15;
  int g = nt >> 1, u = nt & 1;
  int row = g * 512 + jt * 32 + u * 16 + (lane & 15);
  int k0  = kt * 32 + (lane >> 4) * 8;
  const float* src = w + (size_t)row * 512 + k0;
  u16* dst = d + ((size_t)fg) * 512 + lane * 8;
#pragma unroll
  for (int i = 0; i < 8; i++) dst[i] = f2bf(src[i]);
}

// ---------------------------------------------------------------------------
// Persistent weight-resident recurrence. Regular launch, grid = 256 blocks
// (== CU count; co-resident by capacity), 256 threads (4 waves).
// Blocks 0..127: layer0 chunk c; 128..255: layer1 chunk c-1.
// Block (bt 0..7, jt 0..15): 32 batches x 32 j. Wave (mt=w>>1, u=w&1):
// 16 batches x 16 j, all 3 gates. Weights: 48 B-fragments/wave in VGPRs.
// h exchanged in MFMA A-FRAGMENT LAYOUT via hbuf planes; BOTH sides sc0|sc1
// (LLC-coherent) => fence-free barrier. hp (fp32 state) in 4 VGPRs/lane.
// ---------------------------------------------------------------------------
__global__ __launch_bounds__(256, 1)
void coop_rec(int c, int TC, int nc, unsigned bar_base16, unsigned* bar,
              const float* __restrict__ xg0, const float* __restrict__ xg1,
              const u16* __restrict__ wslab0, const u16* __restrict__ wslab1,
              const float* __restrict__ bhh0, const float* __restrict__ bhh1,
              u16* __restrict__ h1seq, u16* __restrict__ hbuf,
              float* __restrict__ carry) {
  const int bid   = blockIdx.x;
  const int layer = bid >> 7;
  const int lb    = bid & 127;
  const int jt    = lb & 15, bt = lb >> 4;
  const int cc    = (layer == 0) ? c : c - 1;
  const bool active = (cc >= 0 && cc < nc);

  unsigned* mybar = bar + (size_t)(layer * 8 + bt) * 64;   // own cacheline

  if (!active) {               // keep the group's counter in lockstep
    for (int t = 0; t < TC; ++t)
      gbar16(mybar, bar_base16 + 16u * (unsigned)(t + 1));
    return;
  }

  const float* xg    = layer ? xg1 : xg0;
  const u16*  wslab  = layer ? wslab1 : wslab0;
  const float* bhh   = layer ? bhh1 : bhh0;
  float* mycarry = carry + (size_t)layer * kB * kH;

  const int tid  = threadIdx.x;
  const int wv   = tid >> 6, lane = tid & 63;
  const int mt   = wv >> 1, u = wv & 1;
  const int b0   = bt * 32;
  const int jl   = lane & 15;
  const int jg   = jt * 32 + u * 16 + jl;        // this lane's output j
  const int mrow = (lane >> 4) * 4;              // first of 4 batch rows

  // --- load this wave's 48 B-fragments into registers (once) ---
  s8v bfr[3][16];
  {
    const u16* base = wslab + (size_t)jt * 96 * 512;
#pragma unroll
    for (int g = 0; g < 3; ++g)
#pragma unroll
      for (int kt = 0; kt < 16; ++kt)
        bfr[g][kt] = *(const s8v*)&base[(size_t)((g * 2 + u) * 16 + kt) * 512 + lane * 8];
  }
  const float bh_r = bhh[jg], bh_z = bhh[512 + jg], bh_n = bhh[1024 + jg];

  // --- fp32 state for this lane's 4 (batch, j) outputs, from carry ---
  float hp[4];
#pragma unroll
  for (int r = 0; r < 4; ++r)
    hp[r] = mycarry[(size_t)(b0 + mt * 16 + mrow + r) * 512 + jg];

  // consumer fragment base (this wave's m-tile, kt=0), producer frag index
  const size_t cons_off = ((size_t)((bt * 2 + mt) * 16)) * 512 + lane * 8;
  const size_t prod_off = ((size_t)((bt * 2 + mt) * 16 + jt)) * 512 +
                          (size_t)(16 * (u * 2 + (jl >> 3))) * 8 + (jl & 7);

  for (int t = 0; t < TC; ++t) {
    // --- xg loads first (independent; drained by the asm's vmcnt(0)) ---
    float xv0[4], xv1[4], xv2[4];
#pragma unroll
    for (int r = 0; r < 4; ++r) {
      int b = b0 + mt * 16 + mrow + r;
      const float* xp = xg + ((size_t)b * TC + t) * kG3;
      xv0[r] = xp[jg]; xv1[r] = xp[512 + jg]; xv2[r] = xp[1024 + jg];
    }

    // --- A-fragments of h_{t-1}: 16 x dwordx4, L1/L2 bypass, one waitcnt ---
    const u16* plane = hbuf + (size_t)(layer * 2 + (t & 1)) * kPlane;
    i4v a[16];
    load_afrag16(plane + cons_off, a);

    // --- MFMA: 3 gates x 16 k-tiles (3 independent chains) ---
    f4v acc0 = {0.f, 0.f, 0.f, 0.f}, acc1 = acc0, acc2 = acc0;
#pragma unroll
    for (int kt = 0; kt < 16; ++kt) {
      const s8v av = __builtin_bit_cast(s8v, a[kt]);
      acc0 = __builtin_amdgcn_mfma_f32_16x16x32_bf16(av, bfr[0][kt], acc0, 0, 0, 0);
      acc1 = __builtin_amdgcn_mfma_f32_16x16x32_bf16(av, bfr[1][kt], acc1, 0, 0, 0);
      acc2 = __builtin_amdgcn_mfma_f32_16x16x32_bf16(av, bfr[2][kt], acc2, 0, 0, 0);
    }

    // --- gates + state update; coherent store into next parity plane ---
    u16* planeN = hbuf + (size_t)(layer * 2 + ((t + 1) & 1)) * kPlane;
#pragma unroll
    for (int r = 0; r < 4; ++r) {
      float rr = fsig(xv0[r] + acc0[r] + bh_r);
      float zz = fsig(xv1[r] + acc1[r] + bh_z);
      float nn = ftanh(xv2[r] + rr * (acc2[r] + bh_n));
      float hn = (1.f - zz) * nn + zz * hp[r];
      hp[r] = hn;
      u16 hb = f2bf(hn);
      store_h_coherent(planeN + prod_off + (size_t)(mrow + r) * 8, hb);
      if (layer == 0)
        h1seq[((size_t)(b0 + mt * 16 + mrow + r) * TC + t) * 512 + jg] = hb;
    }
    gbar16(mybar, bar_base16 + 16u * (unsigned)(t + 1));
  }

  // --- carry writeback (fp32) ---
#pragma unroll
  for (int r = 0; r < 4; ++r)
    mycarry[(size_t)(b0 + mt * 16 + mrow + r) * 512 + jg] = hp[r];
}

// ---- GEMM: C[r][1536] = A[r][K] @ W[1536][K]^T + bias (bf16 MFMA) ----
// Row r -> (b = r/TC, t = r%TC); rowptr = A + (b*Abstride + Atoff + t)*K
__device__ void gemm_role(int idx, int TC,
                          const float* __restrict__ Af, const u16* __restrict__ Ab,
                          int Abstride, int Atoff, int K,
                          const float* __restrict__ Bf, const float* __restrict__ bias,
                          float* __restrict__ C, char* smem) {
  u16* As = (u16*)smem;            // [128][40]
  u16* Bs = As + 128 * 40;         // [128][40]
  const int tid = threadIdx.x;
  const int mt = idx / 12, nt = idx % 12;
  const int m0 = mt * 128, n0 = nt * 128;
  const int w = tid >> 6, lane = tid & 63;
  const int wm = w & 1, wn = w >> 1;
  const int ra = tid >> 2, koff = (tid & 3) * 8;

  const int r = m0 + ra;
  const size_t aoff = ((size_t)(r / TC) * Abstride + Atoff + (r % TC)) * K;
  const float* arowF = Af ? Af + aoff : nullptr;
  const u16*  arowB = Ab ? Ab + aoff : nullptr;
  const float* browF = Bf + (size_t)(n0 + ra) * K;

  f4v acc[4][2];
#pragma unroll
  for (int i = 0; i < 4; i++)
#pragma unroll
    for (int jn = 0; jn < 2; jn++) acc[i][jn] = (f4v){0.f, 0.f, 0.f, 0.f};

  for (int k0 = 0; k0 < K; k0 += 32) {
    s8v av, bv;
    if (arowB) {
      av = *(const s8v*)(arowB + k0 + koff);
    } else {
      u16 tmp[8];
      const float* ap = arowF + k0 + koff;
#pragma unroll
      for (int i = 0; i < 8; i++) tmp[i] = f2bf(ap[i]);
      av = *(s8v*)tmp;
    }
    {
      u16 tmp[8];
      const float* bp = browF + k0 + koff;
#pragma unroll
      for (int i = 0; i < 8; i++) tmp[i] = f2bf(bp[i]);
      bv = *(s8v*)tmp;
    }
    __syncthreads();
    *(s8v*)&As[ra * 40 + koff] = av;
    *(s8v*)&Bs[ra * 40 + koff] = bv;
    __syncthreads();
    s8v af[4];
#pragma unroll
    for (int i = 0; i < 4; i++)
      af[i] = *(const s8v*)&As[(wm * 64 + i * 16 + (lane & 15)) * 40 + (lane >> 4) * 8];
#pragma unroll
    for (int jn = 0; jn < 2; jn++) {
      s8v bf = *(const s8v*)&Bs[(wn * 32 + jn * 16 + (lane & 15)) * 40 + (lane >> 4) * 8];
#pragma unroll
      for (int i = 0; i < 4; i++)
        acc[i][jn] = __builtin_amdgcn_mfma_f32_16x16x32_bf16(af[i], bf, acc[i][jn], 0, 0, 0);
    }
  }

#pragma unroll
  for (int jn = 0; jn < 2; jn++) {
    int n = n0 + wn * 32 + jn * 16 + (lane & 15);
    float bv2 = bias[n];
#pragma unroll
    for (int i = 0; i < 4; i++) {
      int mrow = m0 + wm * 64 + i * 16 + (lane >> 4) * 4;
#pragma unroll
      for (int reg = 0; reg < 4; reg++)
        C[(size_t)(mrow + reg) * kG3 + n] = acc[i][jn][reg] + bv2;
    }
  }
}

__global__ __launch_bounds__(512)
void gemm_kernel(int TC, const float* Af, const u16* Ab, int Abstride, int Atoff,
                 int K, const float* Bf, const float* bias, float* C) {
  __shared__ __align__(16) char smem[2 * 128 * 40 * 2];
  gemm_role(blockIdx.x, TC, Af, Ab, Abstride, Atoff, K, Bf, bias, C, smem);
}

// ---------------------------------------------------------------------------
__global__ __launch_bounds__(128)
void fc_kernel(const float* __restrict__ h, const float* __restrict__ wfc,
               const float* __restrict__ bfc, float* __restrict__ out) {
  const int b = blockIdx.x;
  const int n = threadIdx.x;
  const float* hrow = h + (size_t)b * kH;
  const float* wrow = wfc + (size_t)n * kH;
  float acc = 0.f;
#pragma unroll 4
  for (int k = 0; k < kH; k += 4) {
    const float4 hv = *(const float4*)&hrow[k];
    const float4 wv = *(const float4*)&wrow[k];
    acc = fmaf(hv.x, wv.x, acc); acc = fmaf(hv.y, wv.y, acc);
    acc = fmaf(hv.z, wv.z, acc); acc = fmaf(hv.w, wv.w, acc);
  }
  out[(size_t)b * kNOUT + n] = acc + bfc[n];
}

// ---------------------------------------------------------------------------
extern "C" void kernel_launch(void* const* d_in, const int* in_sizes, int n_in,
                              void* d_out, int out_size, void* d_ws, size_t ws_size,
                              hipStream_t stream) {
  const float* x     = (const float*)d_in[0];
  const float* w_ih0 = (const float*)d_in[1];
  const float* w_hh0 = (const float*)d_in[2];
  const float* b_ih0 = (const float*)d_in[3];
  const float* b_hh0 = (const float*)d_in[4];
  const float* w_ih1 = (const float*)d_in[5];
  const float* w_hh1 = (const float*)d_in[6];
  const float* b_ih1 = (const float*)d_in[7];
  const float* b_hh1 = (const float*)d_in[8];
  const float* w_fc  = (const float*)d_in[9];
  const float* b_fc  = (const float*)d_in[10];
  float* out = (float*)d_out;

  // workspace sizing (TC adaptive; TC=64 needs ~240 MB)
  auto need = [](int tc) -> size_t {
    size_t s = 0;
    s += 2 * (size_t)kB * tc * kG3 * 4;   // xg0 + xg1 fp32
    s += (size_t)kB * tc * kH * 2;        // h1seq bf16
    s += 2 * (size_t)kG3 * kH * 2;        // wslab x2
    s += 4 * (size_t)kPlane * 2;          // hbuf A-frag planes [2 layers][2 parity]
    s += 2 * (size_t)kB * kH * 4;         // carry fp32 x2
    s += 32768;
    return s;
  };
  int TC = 64;
  while (TC > 2 && need(TC) > ws_size) TC >>= 1;
  const int nc = kT / TC;

  char* p = (char*)d_ws;
  auto carve = [&](size_t bytes) {
    char* r = p; p += (bytes + 255) & ~(size_t)255; return r;
  };
  float* xg0   = (float*)carve((size_t)kB * TC * kG3 * 4);
  float* xg1   = (float*)carve((size_t)kB * TC * kG3 * 4);
  u16* h1seq   = (u16*)carve((size_t)kB * TC * kH * 2);
  u16* wslab0  = (u16*)carve((size_t)kG3 * kH * 2);
  u16* wslab1  = (u16*)carve((size_t)kG3 * kH * 2);
  u16* hbuf    = (u16*)carve(4 * (size_t)kPlane * 2);
  float* carry = (float*)carve(2 * (size_t)kB * kH * 4);
  unsigned* bar = (unsigned*)carve(32 * 64 * sizeof(unsigned));  // 32 cachelines

  // prologue: weight swizzle + zero h planes/carries + barrier counters
  build_wslab<<<384, 256, 0, stream>>>(w_hh0, wslab0);
  build_wslab<<<384, 256, 0, stream>>>(w_hh1, wslab1);
  hipMemsetAsync(hbuf, 0, 4 * (size_t)kPlane * 2 + 2 * (size_t)kB * kH * 4, stream);
  hipMemsetAsync(bar, 0, 32 * 64 * sizeof(unsigned), stream);

  const dim3 ggrid(2 * TC * 12);   // (256*TC/128) m-tiles x 12 n-tiles

  for (int c = 0; c <= nc; ++c) {
    if (c < nc) {
      // proj0(c): xg0 = x(chunk c) @ w_ih0^T + b_ih0
      gemm_kernel<<<ggrid, 512, 0, stream>>>(TC, x, nullptr, kT, c * TC, kDIN,
                                             w_ih0, b_ih0, xg0);
    }
    // persistent recurrence: rec0(c) blocks 0..127, rec1(c-1) blocks 128..255
    {
      unsigned base16 = (unsigned)c * 16u * (unsigned)TC;
      coop_rec<<<dim3(256), dim3(256), 0, stream>>>(
          c, TC, nc, base16, bar, xg0, xg1, wslab0, wslab1,
          b_hh0, b_hh1, h1seq, hbuf, carry);
    }
    if (c < nc) {
      // proj1(c): xg1 = h1seq(c) @ w_ih1^T + b_ih1
      gemm_kernel<<<ggrid, 512, 0, stream>>>(TC, nullptr, h1seq, TC, 0, kH,
                                             w_ih1, b_ih1, xg1);
    }
  }

  // final FC on layer-1 carry (fp32)
  fc_kernel<<<dim3(kB), dim3(kNOUT), 0, stream>>>(
      carry + (size_t)kB * kH, w_fc, b_fc, out);
}

// Round 9
// 2612.370 us; speedup vs baseline: 8.8752x; 1.2398x over previous
//
#include <hip/hip_runtime.h>
#include <math.h>

typedef unsigned short u16;
typedef __attribute__((ext_vector_type(8))) short s8v;   // 8 x bf16 (4 VGPRs)
typedef __attribute__((ext_vector_type(4))) float f4v;   // MFMA accumulator
typedef __attribute__((ext_vector_type(4))) int   i4v;   // asm load payload

constexpr int kB    = 256;
constexpr int kT    = 512;
constexpr int kDIN  = 64;
constexpr int kH    = 512;
constexpr int kG3   = 1536;
constexpr int kNOUT = 128;
constexpr int kPlane = 8 * 2 * 16 * 512;   // u16 per A-frag plane (131072)

__device__ __forceinline__ u16 f2bf(float f) {   // round-to-nearest-even
  union { float f; unsigned u; } v; v.f = f;
  unsigned r = (v.u + 0x7FFFu + ((v.u >> 16) & 1u)) >> 16;
  return (u16)r;
}
__device__ __forceinline__ float fsig(float x) {
  x = fminf(fmaxf(x, -30.f), 30.f);
  float e = __expf(-x);
  return __fdividef(1.f, 1.f + e);
}
__device__ __forceinline__ float ftanh(float x) {
  x = fminf(fmaxf(x, -15.f), 15.f);
  float e = __expf(-2.f * x);
  return __fdividef(1.f - e, 1.f + e);
}

// 16 A-fragment loads (16 B/lane each, kt stride 1024 B), L1/L2 bypass,
// one vmcnt(0) at the end — full memory-level parallelism.
__device__ __forceinline__ void load_afrag16(const u16* base, i4v a[16]) {
  asm volatile(
      "global_load_dwordx4 %0, %16, off sc0 sc1\n\t"
      "global_load_dwordx4 %1, %16, off offset:1024 sc0 sc1\n\t"
      "global_load_dwordx4 %2, %16, off offset:2048 sc0 sc1\n\t"
      "global_load_dwordx4 %3, %16, off offset:3072 sc0 sc1\n\t"
      "global_load_dwordx4 %4, %17, off sc0 sc1\n\t"
      "global_load_dwordx4 %5, %17, off offset:1024 sc0 sc1\n\t"
      "global_load_dwordx4 %6, %17, off offset:2048 sc0 sc1\n\t"
      "global_load_dwordx4 %7, %17, off offset:3072 sc0 sc1\n\t"
      "global_load_dwordx4 %8, %18, off sc0 sc1\n\t"
      "global_load_dwordx4 %9, %18, off offset:1024 sc0 sc1\n\t"
      "global_load_dwordx4 %10, %18, off offset:2048 sc0 sc1\n\t"
      "global_load_dwordx4 %11, %18, off offset:3072 sc0 sc1\n\t"
      "global_load_dwordx4 %12, %19, off sc0 sc1\n\t"
      "global_load_dwordx4 %13, %19, off offset:1024 sc0 sc1\n\t"
      "global_load_dwordx4 %14, %19, off offset:2048 sc0 sc1\n\t"
      "global_load_dwordx4 %15, %19, off offset:3072 sc0 sc1\n\t"
      "s_waitcnt vmcnt(0)"
      : "=&v"(a[0]), "=&v"(a[1]), "=&v"(a[2]), "=&v"(a[3]),
        "=&v"(a[4]), "=&v"(a[5]), "=&v"(a[6]), "=&v"(a[7]),
        "=&v"(a[8]), "=&v"(a[9]), "=&v"(a[10]), "=&v"(a[11]),
        "=&v"(a[12]), "=&v"(a[13]), "=&v"(a[14]), "=&v"(a[15])
      : "v"(base), "v"(base + 4 * 512), "v"(base + 8 * 512), "v"(base + 12 * 512)
      : "memory");
}

// Layer-0 epilogue stores: 4 coherent hbuf stores FIRST, then 4 plain h1seq
// stores, then vmcnt(4) — waits only for the hbuf (oldest) 4; h1seq drains
// during the barrier round (vmcnt retires in issue order, m135).
__device__ __forceinline__ void store_h_l0(
    u16* p0, u16* p1, u16* p2, u16* p3,
    u16* q0, u16* q1, u16* q2, u16* q3,
    unsigned v0, unsigned v1, unsigned v2, unsigned v3) {
  asm volatile(
      "global_store_short %0, %8, off sc0 sc1\n\t"
      "global_store_short %1, %9, off sc0 sc1\n\t"
      "global_store_short %2, %10, off sc0 sc1\n\t"
      "global_store_short %3, %11, off sc0 sc1\n\t"
      "global_store_short %4, %8, off\n\t"
      "global_store_short %5, %9, off\n\t"
      "global_store_short %6, %10, off\n\t"
      "global_store_short %7, %11, off\n\t"
      "s_waitcnt vmcnt(4)"
      :: "v"(p0), "v"(p1), "v"(p2), "v"(p3),
         "v"(q0), "v"(q1), "v"(q2), "v"(q3),
         "v"(v0), "v"(v1), "v"(v2), "v"(v3)
      : "memory");
}
// Layer-1: 4 coherent stores + full drain.
__device__ __forceinline__ void store_h_l1(
    u16* p0, u16* p1, u16* p2, u16* p3,
    unsigned v0, unsigned v1, unsigned v2, unsigned v3) {
  asm volatile(
      "global_store_short %0, %4, off sc0 sc1\n\t"
      "global_store_short %1, %5, off sc0 sc1\n\t"
      "global_store_short %2, %6, off sc0 sc1\n\t"
      "global_store_short %3, %7, off sc0 sc1\n\t"
      "s_waitcnt vmcnt(0)"
      :: "v"(p0), "v"(p1), "v"(p2), "v"(p3),
         "v"(v0), "v"(v1), "v"(v2), "v"(v3)
      : "memory");
}

// ---------------------------------------------------------------------------
// Pre-swizzle w_hh [1536][512] fp32 -> per-block-slice B-fragment slabs (bf16).
// Slab layout: [jt 16][f 96][lane 64][8],  f = nt*16 + kt,  nt = g*2 + u.
// elem: row = g*512 + jt*32 + u*16 + (lane&15), k = kt*32 + (lane>>4)*8 + i
// ---------------------------------------------------------------------------
__global__ void build_wslab(const float* __restrict__ w, u16* __restrict__ d) {
  int idx  = blockIdx.x * 256 + threadIdx.x;   // 0..98303
  int lane = idx & 63, fg = idx >> 6;          // fg = jt*96 + f
  int jt = fg / 96, f = fg % 96;
  int nt = f >> 4, kt = f & 15;
  int g = nt >> 1, u = nt & 1;
  int row = g * 512 + jt * 32 + u * 16 + (lane & 15);
  int k0  = kt * 32 + (lane >> 4) * 8;
  const float* src = w + (size_t)row * 512 + k0;
  u16* dst = d + ((size_t)fg) * 512 + lane * 8;
#pragma unroll
  for (int i = 0; i < 8; i++) dst[i] = f2bf(src[i]);
}

// ---------------------------------------------------------------------------
// Persistent weight-resident recurrence. Regular launch, grid = 256 blocks
// (== CU count; co-resident by capacity), 256 threads (4 waves).
// Blocks 0..127: layer0 chunk c; 128..255: layer1 chunk c-1.
// Block (bt 0..7, jt 0..15): 32 batches x 32 j. Wave (mt=w>>1, u=w&1):
// 16 batches x 16 j, all 3 gates. Weights: 48 B-fragments/wave.
// h exchanged in MFMA A-FRAGMENT LAYOUT via hbuf planes; sc0|sc1 both sides
// (LLC-coherent) => fence-free split-phase barrier:
//   [wait(t)] -> frag loads -> MFMA -> epilogue -> publish -> arrive(t)
//   -> prefetch xg(t+1) (flies during next wait).
// ---------------------------------------------------------------------------
__global__ __launch_bounds__(256, 1)
void coop_rec(int c, int TC, int nc, unsigned bar_base16, unsigned* bar,
              const float* __restrict__ xg0, const float* __restrict__ xg1,
              const u16* __restrict__ wslab0, const u16* __restrict__ wslab1,
              const float* __restrict__ bhh0, const float* __restrict__ bhh1,
              u16* __restrict__ h1seq, u16* __restrict__ hbuf,
              float* __restrict__ carry) {
  const int bid   = blockIdx.x;
  const int layer = bid >> 7;
  const int lb    = bid & 127;
  const int jt    = lb & 15, bt = lb >> 4;
  const int cc    = (layer == 0) ? c : c - 1;
  const bool active = (cc >= 0 && cc < nc);

  unsigned* mybar = bar + (size_t)(layer * 8 + bt) * 64;   // own cacheline

  if (!active) {   // whole (layer,bt) group inactive together: fast-forward
    if (threadIdx.x == 0)
      __hip_atomic_fetch_add(mybar, (unsigned)TC, __ATOMIC_RELAXED,
                             __HIP_MEMORY_SCOPE_AGENT);
    return;
  }

  const float* xg    = layer ? xg1 : xg0;
  const u16*  wslab  = layer ? wslab1 : wslab0;
  const float* bhh   = layer ? bhh1 : bhh0;
  float* mycarry = carry + (size_t)layer * kB * kH;

  const int tid  = threadIdx.x;
  const int wv   = tid >> 6, lane = tid & 63;
  const int mt   = wv >> 1, u = wv & 1;
  const int b0   = bt * 32;
  const int jl   = lane & 15;
  const int jg   = jt * 32 + u * 16 + jl;        // this lane's output j
  const int mrow = (lane >> 4) * 4;              // first of 4 batch rows

  // --- load this wave's 48 B-fragments into registers (once) ---
  s8v bfr[3][16];
  {
    const u16* base = wslab + (size_t)jt * 96 * 512;
#pragma unroll
    for (int g = 0; g < 3; ++g)
#pragma unroll
      for (int kt = 0; kt < 16; ++kt)
        bfr[g][kt] = *(const s8v*)&base[(size_t)((g * 2 + u) * 16 + kt) * 512 + lane * 8];
  }
  const float bh_r = bhh[jg], bh_z = bhh[512 + jg], bh_n = bhh[1024 + jg];

  // --- fp32 state for this lane's 4 (batch, j) outputs, from carry ---
  float hp[4];
#pragma unroll
  for (int r = 0; r < 4; ++r)
    hp[r] = mycarry[(size_t)(b0 + mt * 16 + mrow + r) * 512 + jg];

  // consumer fragment base (this wave's m-tile, kt=0), producer frag index
  const size_t cons_off = ((size_t)((bt * 2 + mt) * 16)) * 512 + lane * 8;
  const size_t prod_off = ((size_t)((bt * 2 + mt) * 16 + jt)) * 512 +
                          (size_t)(16 * (u * 2 + (jl >> 3))) * 8 + (jl & 7);
  const int bbase = b0 + mt * 16 + mrow;   // first batch row of this lane

  float xv0[4], xv1[4], xv2[4];
  auto prefetch_xg = [&](int tt) {
#pragma unroll
    for (int r = 0; r < 4; ++r) {
      const float* xp = xg + ((size_t)(bbase + r) * TC + tt) * kG3;
      xv0[r] = xp[jg]; xv1[r] = xp[512 + jg]; xv2[r] = xp[1024 + jg];
    }
  };
  prefetch_xg(0);

  for (int t = 0; t < TC; ++t) {
    // --- wait phase: all step-(t-1) publishes visible (no-op at t==0) ---
    if (tid == 0) {
      unsigned tgt = bar_base16 + 16u * (unsigned)t;
      int guard = 0;
      while (__hip_atomic_load(mybar, __ATOMIC_RELAXED,
                               __HIP_MEMORY_SCOPE_AGENT) < tgt
             && ++guard < (1 << 21)) {
        __builtin_amdgcn_s_sleep(1);
      }
    }
    __syncthreads();

    // --- A-fragments of h_{t-1}: 16 x dwordx4 bypass; vmcnt(0) also drains
    //     the xg prefetch issued last iteration ---
    const u16* plane = hbuf + (size_t)(layer * 2 + (t & 1)) * kPlane;
    i4v a[16];
    load_afrag16(plane + cons_off, a);

    // --- MFMA: 3 gates x 16 k-tiles (3 independent chains) ---
    f4v acc0 = {0.f, 0.f, 0.f, 0.f}, acc1 = acc0, acc2 = acc0;
#pragma unroll
    for (int kt = 0; kt < 16; ++kt) {
      const s8v av = __builtin_bit_cast(s8v, a[kt]);
      acc0 = __builtin_amdgcn_mfma_f32_16x16x32_bf16(av, bfr[0][kt], acc0, 0, 0, 0);
      acc1 = __builtin_amdgcn_mfma_f32_16x16x32_bf16(av, bfr[1][kt], acc1, 0, 0, 0);
      acc2 = __builtin_amdgcn_mfma_f32_16x16x32_bf16(av, bfr[2][kt], acc2, 0, 0, 0);
    }

    // --- gates + state update ---
    unsigned hv[4];
#pragma unroll
    for (int r = 0; r < 4; ++r) {
      float rr = fsig(xv0[r] + acc0[r] + bh_r);
      float zz = fsig(xv1[r] + acc1[r] + bh_z);
      float nn = ftanh(xv2[r] + rr * (acc2[r] + bh_n));
      float hn = (1.f - zz) * nn + zz * hp[r];
      hp[r] = hn;
      hv[r] = f2bf(hn);
    }

    // --- publish h_t (hbuf coherent; h1seq trailing) ---
    u16* pb = hbuf + (size_t)(layer * 2 + ((t + 1) & 1)) * kPlane + prod_off;
    if (layer == 0) {
      u16* q = h1seq + ((size_t)bbase * TC + t) * 512 + jg;
      store_h_l0(pb + (size_t)(mrow + 0) * 8, pb + (size_t)(mrow + 1) * 8,
                 pb + (size_t)(mrow + 2) * 8, pb + (size_t)(mrow + 3) * 8,
                 q, q + (size_t)TC * 512, q + 2 * (size_t)TC * 512,
                 q + 3 * (size_t)TC * 512,
                 hv[0], hv[1], hv[2], hv[3]);
    } else {
      store_h_l1(pb + (size_t)(mrow + 0) * 8, pb + (size_t)(mrow + 1) * 8,
                 pb + (size_t)(mrow + 2) * 8, pb + (size_t)(mrow + 3) * 8,
                 hv[0], hv[1], hv[2], hv[3]);
    }
    __syncthreads();                 // all waves' publishes drained
    if (tid == 0)
      __hip_atomic_fetch_add(mybar, 1u, __ATOMIC_RELAXED,
                             __HIP_MEMORY_SCOPE_AGENT);
    if (t + 1 < TC) prefetch_xg(t + 1);   // flies during next wait phase
  }

  // --- carry writeback (fp32) ---
#pragma unroll
  for (int r = 0; r < 4; ++r)
    mycarry[(size_t)(bbase + r) * 512 + jg] = hp[r];
}

// ---- GEMM: C[r][1536] = A[r][K] @ W[1536][K]^T + bias (bf16 MFMA) ----
// Row r -> (b = r/TC, t = r%TC); rowptr = A + (b*Abstride + Atoff + t)*K
__device__ void gemm_role(int idx, int TC,
                          const float* __restrict__ Af, const u16* __restrict__ Ab,
                          int Abstride, int Atoff, int K,
                          const float* __restrict__ Bf, const float* __restrict__ bias,
                          float* __restrict__ C, char* smem) {
  u16* As = (u16*)smem;            // [128][40]
  u16* Bs = As + 128 * 40;         // [128][40]
  const int tid = threadIdx.x;
  const int mt = idx / 12, nt = idx % 12;
  const int m0 = mt * 128, n0 = nt * 128;
  const int w = tid >> 6, lane = tid & 63;
  const int wm = w & 1, wn = w >> 1;
  const int ra = tid >> 2, koff = (tid & 3) * 8;

  const int r = m0 + ra;
  const size_t aoff = ((size_t)(r / TC) * Abstride + Atoff + (r % TC)) * K;
  const float* arowF = Af ? Af + aoff : nullptr;
  const u16*  arowB = Ab ? Ab + aoff : nullptr;
  const float* browF = Bf + (size_t)(n0 + ra) * K;

  f4v acc[4][2];
#pragma unroll
  for (int i = 0; i < 4; i++)
#pragma unroll
    for (int jn = 0; jn < 2; jn++) acc[i][jn] = (f4v){0.f, 0.f, 0.f, 0.f};

  for (int k0 = 0; k0 < K; k0 += 32) {
    s8v av, bv;
    if (arowB) {
      av = *(const s8v*)(arowB + k0 + koff);
    } else {
      u16 tmp[8];
      const float* ap = arowF + k0 + koff;
#pragma unroll
      for (int i = 0; i < 8; i++) tmp[i] = f2bf(ap[i]);
      av = *(s8v*)tmp;
    }
    {
      u16 tmp[8];
      const float* bp = browF + k0 + koff;
#pragma unroll
      for (int i = 0; i < 8; i++) tmp[i] = f2bf(bp[i]);
      bv = *(s8v*)tmp;
    }
    __syncthreads();
    *(s8v*)&As[ra * 40 + koff] = av;
    *(s8v*)&Bs[ra * 40 + koff] = bv;
    __syncthreads();
    s8v af[4];
#pragma unroll
    for (int i = 0; i < 4; i++)
      af[i] = *(const s8v*)&As[(wm * 64 + i * 16 + (lane & 15)) * 40 + (lane >> 4) * 8];
#pragma unroll
    for (int jn = 0; jn < 2; jn++) {
      s8v bf = *(const s8v*)&Bs[(wn * 32 + jn * 16 + (lane & 15)) * 40 + (lane >> 4) * 8];
#pragma unroll
      for (int i = 0; i < 4; i++)
        acc[i][jn] = __builtin_amdgcn_mfma_f32_16x16x32_bf16(af[i], bf, acc[i][jn], 0, 0, 0);
    }
  }

#pragma unroll
  for (int jn = 0; jn < 2; jn++) {
    int n = n0 + wn * 32 + jn * 16 + (lane & 15);
    float bv2 = bias[n];
#pragma unroll
    for (int i = 0; i < 4; i++) {
      int mrow = m0 + wm * 64 + i * 16 + (lane >> 4) * 4;
#pragma unroll
      for (int reg = 0; reg < 4; reg++)
        C[(size_t)(mrow + reg) * kG3 + n] = acc[i][jn][reg] + bv2;
    }
  }
}

__global__ __launch_bounds__(512)
void gemm_kernel(int TC, const float* Af, const u16* Ab, int Abstride, int Atoff,
                 int K, const float* Bf, const float* bias, float* C) {
  __shared__ __align__(16) char smem[2 * 128 * 40 * 2];
  gemm_role(blockIdx.x, TC, Af, Ab, Abstride, Atoff, K, Bf, bias, C, smem);
}

// Combined dispatch: blocks [0,G1) do proj1(c) (h1seq -> xg1); blocks
// [G1,2*G1) do proj0(c+1) (x -> xg0) when do0 != 0. Concurrent, one launch.
__global__ __launch_bounds__(512)
void gemm2_kernel(int TC, int G1, int do0,
                  const float* x, int atoff0, const u16* h1seq,
                  const float* wih0, const float* bih0, float* xg0,
                  const float* wih1, const float* bih1, float* xg1) {
  __shared__ __align__(16) char smem[2 * 128 * 40 * 2];
  if ((int)blockIdx.x < G1) {
    gemm_role(blockIdx.x, TC, nullptr, h1seq, TC, 0, kH, wih1, bih1, xg1, smem);
  } else if (do0) {
    gemm_role(blockIdx.x - G1, TC, x, nullptr, kT, atoff0, kDIN, wih0, bih0,
              xg0, smem);
  }
}

// ---------------------------------------------------------------------------
__global__ __launch_bounds__(128)
void fc_kernel(const float* __restrict__ h, const float* __restrict__ wfc,
               const float* __restrict__ bfc, float* __restrict__ out) {
  const int b = blockIdx.x;
  const int n = threadIdx.x;
  const float* hrow = h + (size_t)b * kH;
  const float* wrow = wfc + (size_t)n * kH;
  float acc = 0.f;
#pragma unroll 4
  for (int k = 0; k < kH; k += 4) {
    const float4 hv = *(const float4*)&hrow[k];
    const float4 wv = *(const float4*)&wrow[k];
    acc = fmaf(hv.x, wv.x, acc); acc = fmaf(hv.y, wv.y, acc);
    acc = fmaf(hv.z, wv.z, acc); acc = fmaf(hv.w, wv.w, acc);
  }
  out[(size_t)b * kNOUT + n] = acc + bfc[n];
}

// ---------------------------------------------------------------------------
extern "C" void kernel_launch(void* const* d_in, const int* in_sizes, int n_in,
                              void* d_out, int out_size, void* d_ws, size_t ws_size,
                              hipStream_t stream) {
  const float* x     = (const float*)d_in[0];
  const float* w_ih0 = (const float*)d_in[1];
  const float* w_hh0 = (const float*)d_in[2];
  const float* b_ih0 = (const float*)d_in[3];
  const float* b_hh0 = (const float*)d_in[4];
  const float* w_ih1 = (const float*)d_in[5];
  const float* w_hh1 = (const float*)d_in[6];
  const float* b_ih1 = (const float*)d_in[7];
  const float* b_hh1 = (const float*)d_in[8];
  const float* w_fc  = (const float*)d_in[9];
  const float* b_fc  = (const float*)d_in[10];
  float* out = (float*)d_out;

  // workspace sizing (TC adaptive; TC=64 needs ~240 MB)
  auto need = [](int tc) -> size_t {
    size_t s = 0;
    s += 2 * (size_t)kB * tc * kG3 * 4;   // xg0 + xg1 fp32
    s += (size_t)kB * tc * kH * 2;        // h1seq bf16
    s += 2 * (size_t)kG3 * kH * 2;        // wslab x2
    s += 4 * (size_t)kPlane * 2;          // hbuf A-frag planes [2 layers][2 parity]
    s += 2 * (size_t)kB * kH * 4;         // carry fp32 x2
    s += 32768;
    return s;
  };
  int TC = 64;
  while (TC > 2 && need(TC) > ws_size) TC >>= 1;
  const int nc = kT / TC;

  char* p = (char*)d_ws;
  auto carve = [&](size_t bytes) {
    char* r = p; p += (bytes + 255) & ~(size_t)255; return r;
  };
  float* xg0   = (float*)carve((size_t)kB * TC * kG3 * 4);
  float* xg1   = (float*)carve((size_t)kB * TC * kG3 * 4);
  u16* h1seq   = (u16*)carve((size_t)kB * TC * kH * 2);
  u16* wslab0  = (u16*)carve((size_t)kG3 * kH * 2);
  u16* wslab1  = (u16*)carve((size_t)kG3 * kH * 2);
  u16* hbuf    = (u16*)carve(4 * (size_t)kPlane * 2);
  float* carry = (float*)carve(2 * (size_t)kB * kH * 4);
  unsigned* bar = (unsigned*)carve(32 * 64 * sizeof(unsigned));  // 32 cachelines

  // prologue: weight swizzle + zero h planes/carries + barrier counters
  build_wslab<<<384, 256, 0, stream>>>(w_hh0, wslab0);
  build_wslab<<<384, 256, 0, stream>>>(w_hh1, wslab1);
  hipMemsetAsync(hbuf, 0, 4 * (size_t)kPlane * 2 + 2 * (size_t)kB * kH * 4, stream);
  hipMemsetAsync(bar, 0, 32 * 64 * sizeof(unsigned), stream);

  const int G1 = 24 * TC;   // proj tiles per matrix: 2TC m-tiles x 12 n-tiles

  // proj0(0): xg0 = x(chunk 0) @ w_ih0^T + b_ih0
  gemm_kernel<<<dim3(G1), 512, 0, stream>>>(TC, x, nullptr, kT, 0, kDIN,
                                            w_ih0, b_ih0, xg0);

  for (int c = 0; c <= nc; ++c) {
    // persistent recurrence: rec0(c) blocks 0..127, rec1(c-1) blocks 128..255
    unsigned base16 = (unsigned)c * 16u * (unsigned)TC;
    coop_rec<<<dim3(256), dim3(256), 0, stream>>>(
        c, TC, nc, base16, bar, xg0, xg1, wslab0, wslab1,
        b_hh0, b_hh1, h1seq, hbuf, carry);
    if (c < nc) {
      // proj1(c) + proj0(c+1) fused in one concurrent dispatch
      int do0 = (c + 1 < nc) ? 1 : 0;
      gemm2_kernel<<<dim3(2 * G1), 512, 0, stream>>>(
          TC, G1, do0, x, (c + 1) * TC, h1seq,
          w_ih0, b_ih0, xg0, w_ih1, b_ih1, xg1);
    }
  }

  // final FC on layer-1 carry (fp32)
  fc_kernel<<<dim3(kB), dim3(kNOUT), 0, stream>>>(
      carry + (size_t)kB * kH, w_fc, b_fc, out);
}